// Round 13
// baseline (190.463 us; speedup 1.0000x reference)
//
#include <hip/hip_runtime.h>
#include <math.h>

// B=16, C=128, H=128, W=128, MODES=16, RANK=8
// ws layout (float offsets):
//   tab  @ 0      : 8 tables of 2048 floats each
//   xtop @ 16384  : (b, i, mn, {re,im})  1,048,576 floats
//   z    @ 1064960: 256 floats
//   otop @ 1065216: 1,048,576 floats
//   tf   @ 2113792: split-bf16 F1 DFT table [part][n'][k], 8192 shorts
//   t2f  @ 2117888: bf16 I2 table in frag layout [w][n'], 4096 shorts
//   swf  @ 2119936: split-bf16 skip_w in MFMA A-frag order, 32768 shorts
#define TAB_OFF 0
#define XTOP_OFF 16384
#define Z_OFF (16384 + 1048576)
#define OTOP_OFF (Z_OFF + 256)
#define TF_OFF (OTOP_OFF + 1048576)
#define T2F_OFF (TF_OFF + 4096)
#define SWF_OFF (T2F_OFF + 2048)

using bf16x8 = __attribute__((ext_vector_type(8))) short;
using s16x4  = __attribute__((ext_vector_type(4))) short;
using f32x16 = __attribute__((ext_vector_type(16))) float;

__device__ inline unsigned short bf_rnd(float v) {
  return (unsigned short)((__float_as_uint(v) + 0x8000u) >> 16);
}
__device__ inline void bf_split(float v, unsigned short& hi, unsigned short& lo) {
  unsigned u = __float_as_uint(v);
  hi = (unsigned short)(u >> 16);
  float r = v - __uint_as_float(u & 0xFFFF0000u);
  lo = (unsigned short)(__float_as_uint(r) >> 16);
}
__device__ inline bf16x8 ldfrag(const unsigned short* p) {
  s16x4 a = *(const s16x4*)p;        // ds_read_b64 (8B aligned)
  s16x4 b = *(const s16x4*)(p + 4);
  bf16x8 r;
  r[0] = a[0]; r[1] = a[1]; r[2] = a[2]; r[3] = a[3];
  r[4] = b[0]; r[5] = b[1]; r[6] = b[2]; r[7] = b[3];
  return r;
}
__device__ inline bf16x8 ldfrag_sw(const unsigned short* base, int row, int koff) {
  int byte = row * 256 + ((koff * 2) ^ ((row & 7) << 4));
  return ldfrag((const unsigned short*)((const char*)base + byte));
}

// One merged prep kernel: tab (16384) | tf (4096) | t2f (4096) | swf (16384).
__global__ __launch_bounds__(256) void k_prep(const float* __restrict__ sw,
                                              float* __restrict__ tab,
                                              unsigned short* __restrict__ tf,
                                              unsigned short* __restrict__ t2f,
                                              unsigned short* __restrict__ swf) {
  int idx = blockIdx.x * 256 + threadIdx.x;   // [0, 40960)
  if (idx < 16384) {
    int which = idx >> 11, rem = idx & 2047;
    int a, j;
    if (which == 4 || which == 5) { a = rem & 127; j = rem >> 7; }  // [m][h]
    else { a = rem >> 4; j = rem & 15; }
    int p = (a * j) & 127;
    float ang = (float)p * (float)(3.14159265358979323846 / 64.0);
    float cv = cosf(ang), sv = sinf(ang);
    float v;
    switch (which) {
      case 0: v = cv * (1.f / 128.f); break;
      case 1: v = -sv * (1.f / 128.f); break;
      case 2: v = cv; break;
      case 3: v = sv; break;
      case 4: v = cv; break;
      case 5: v = sv; break;
      case 6: v = ((rem & 15) == 0 ? 1.f : 2.f) * cv * (1.f / 128.f); break;
      default: v = ((rem & 15) == 0 ? 1.f : 2.f) * (-sv) * (1.f / 128.f); break;
    }
    tab[idx] = v;
  } else if (idx < 20480) {
    int r = idx - 16384;                       // [0,4096)
    int np = r >> 7, k = r & 127;
    int n = np & 15;
    int p = (k * n) & 127;
    float ang = (float)p * (float)(3.14159265358979323846 / 64.0);
    float v = (np < 16 ? cosf(ang) : -sinf(ang)) * (1.f / 128.f);
    unsigned short hi, lo;
    bf_split(v, hi, lo);
    tf[np * 128 + k] = hi;
    tf[4096 + np * 128 + k] = lo;
  } else if (idx < 24576) {
    int r = idx - 20480;                       // [0,4096)
    int w = r >> 5, np = r & 31;
    int n = np & 15;
    int p = (w * n) & 127;
    float ang = (float)p * (float)(3.14159265358979323846 / 64.0);
    float cn = (n == 0) ? 1.f : 2.f;
    float v = (np < 16 ? cosf(ang) : -sinf(ang)) * cn * (1.f / 128.f);
    t2f[r] = bf_rnd(v);
  } else {
    int r = idx - 24576;                       // [0,16384)
    int o = r >> 7, k = r & 127;
    unsigned short hb, lb;
    bf_split(sw[o * 128 + k], hb, lb);
    int kc = k >> 5, ks = (k >> 4) & 1, kh = (k >> 3) & 1, j = k & 7;
    int f0 = (kc * 2 + ks) * 2;
    swf[(f0 + 0) * 2048 + o * 16 + kh * 8 + j] = hb;
    swf[(f0 + 1) * 2048 + o * 16 + kh * 8 + j] = lb;
  }
}

// Forward truncated DFT via MFMA + fused z-partials (verified round 11)
__global__ __launch_bounds__(256) void k_fwd(const float* __restrict__ x,
                                             const unsigned short* __restrict__ tf,
                                             const float* __restrict__ tab,
                                             const float* __restrict__ vre,
                                             const float* __restrict__ vim,
                                             float* __restrict__ xtop,
                                             float* __restrict__ zout) {
  __shared__ unsigned short Xh[128 * 128];
  __shared__ unsigned short Tfh[32 * 128];
  __shared__ unsigned short Tfl[32 * 128];
  __shared__ float red[4][16];
  const int c = blockIdx.x, b = blockIdx.y;
  const int t = threadIdx.x;
  const int lane = t & 63, wv = t >> 6;

  #pragma unroll
  for (int it = 0; it < 32; ++it) {
    int idx = it * 256 + t;
    int part = idx >> 12, rem = idx & 4095;
    int row = rem >> 7, k = rem & 127;
    unsigned short v = tf[part * 4096 + rem];
    unsigned short* dst = part ? Tfl : Tfh;
    *(unsigned short*)((char*)dst + row * 256 + ((k * 2) ^ ((row & 7) << 4))) = v;
  }
  const float* img = x + (((size_t)(b * 128 + c)) << 14);
  #pragma unroll
  for (int it = 0; it < 16; ++it) {
    int flat = it * 256 + t;
    int h = flat >> 5, wq = flat & 31;
    float4 v = *(const float4*)(img + (size_t)flat * 4);
    s16x4 pk;
    pk[0] = (short)bf_rnd(v.x); pk[1] = (short)bf_rnd(v.y);
    pk[2] = (short)bf_rnd(v.z); pk[3] = (short)bf_rnd(v.w);
    *(s16x4*)((char*)Xh + h * 256 + ((wq * 8) ^ ((h & 7) << 4))) = pk;
  }
  __syncthreads();

  f32x16 acc;
  #pragma unroll
  for (int e = 0; e < 16; ++e) acc[e] = 0.f;
  const int orow = wv * 32 + (lane & 31);
  const int bcol = lane & 31;
  const int kh8 = (lane >> 5) * 8;
  #pragma unroll
  for (int kc8 = 0; kc8 < 8; ++kc8) {
    int kfull = kc8 * 16 + kh8;
    bf16x8 a  = ldfrag_sw(Xh, orow, kfull);
    bf16x8 th = ldfrag_sw(Tfh, bcol, kfull);
    bf16x8 tl = ldfrag_sw(Tfl, bcol, kfull);
    acc = __builtin_amdgcn_mfma_f32_32x32x16_bf16(a, th, acc, 0, 0, 0);
    acc = __builtin_amdgcn_mfma_f32_32x32x16_bf16(a, tl, acc, 0, 0, 0);
  }
  __syncthreads();

  float* Arp = (float*)Xh;          // [16][132]
  float* Aip = Arp + 16 * 132;
  {
    const int col = lane & 31;
    #pragma unroll
    for (int r = 0; r < 16; ++r) {
      int h = wv * 32 + (r & 3) + 8 * (r >> 2) + 4 * (lane >> 5);
      if (col < 16) Arp[col * 132 + h] = acc[r];
      else          Aip[(col - 16) * 132 + h] = acc[r];
    }
  }
  __syncthreads();

  // ---- F2: thread t -> (m=t>>4, n=t&15), i.e. mn = t ----
  float xr = 0.f, xi = 0.f;
  {
    const int m = t >> 4, n = t & 15;
    const float* tc = tab + 8192 + m * 128;
    const float* ts = tab + 10240 + m * 128;
    const float* ar = Arp + n * 132;
    const float* ai = Aip + n * 132;
    #pragma unroll 8
    for (int h4 = 0; h4 < 128; h4 += 4) {
      float4 av = *(const float4*)(ar + h4);
      float4 iv = *(const float4*)(ai + h4);
      float4 cv = *(const float4*)(tc + h4);
      float4 sv = *(const float4*)(ts + h4);
      xr += av.x * cv.x + iv.x * sv.x;  xi += iv.x * cv.x - av.x * sv.x;
      xr += av.y * cv.y + iv.y * sv.y;  xi += iv.y * cv.y - av.y * sv.y;
      xr += av.z * cv.z + iv.z * sv.z;  xi += iv.z * cv.z - av.z * sv.z;
      xr += av.w * cv.w + iv.w * sv.w;  xi += iv.w * cv.w - av.w * sv.w;
    }
    size_t base = ((size_t)(b * 128 + c)) * 512 + (size_t)t * 2;
    xtop[base] = xr; xtop[base + 1] = xi;
  }

  // ---- fused z partial: z[b,r] += X[b,c,t] * conj(V)[c,r,t] ----
  {
    float zr[8], zi[8];
    #pragma unroll
    for (int r = 0; r < 8; ++r) {
      float vr = vre[(size_t)(c * 8 + r) * 256 + t];
      float vi = vim[(size_t)(c * 8 + r) * 256 + t];
      zr[r] = xr * vr + xi * vi;
      zi[r] = xi * vr - xr * vi;
    }
    #pragma unroll
    for (int r = 0; r < 8; ++r)
      for (int off = 32; off > 0; off >>= 1) {
        zr[r] += __shfl_down(zr[r], off);
        zi[r] += __shfl_down(zi[r], off);
      }
    if (lane == 0) {
      #pragma unroll
      for (int r = 0; r < 8; ++r) { red[wv][r * 2] = zr[r]; red[wv][r * 2 + 1] = zi[r]; }
    }
    __syncthreads();
    if (t < 16) atomicAdd(&zout[b * 16 + t], red[0][t] + red[1][t] + red[2][t] + red[3][t]);
  }
}

// otop partials. vs round 12: b-group 2 -> 4 (each W element now read by 4
// blocks instead of 8 -> L2/L3 W traffic halves, 256 -> 128 MB logical).
// Grid (32 o-tiles, 4 b-quads, 8 ichunks) = 1024 blocks.
__global__ __launch_bounds__(256) void k_mix(const float* __restrict__ xtop,
                                             const float* __restrict__ wre,
                                             const float* __restrict__ wim,
                                             const float* __restrict__ ure,
                                             const float* __restrict__ uim,
                                             const float* __restrict__ z,
                                             float* __restrict__ otop) {
  int o0 = blockIdx.x * 4, b0 = blockIdx.y * 4, ic = blockIdx.z, t = threadIdx.x;
  float ar[4][4], ai[4][4];
  #pragma unroll
  for (int bb = 0; bb < 4; ++bb)
    #pragma unroll
    for (int oo = 0; oo < 4; ++oo) { ar[bb][oo] = 0.f; ai[bb][oo] = 0.f; }
  const float* xp[4];
  #pragma unroll
  for (int bb = 0; bb < 4; ++bb)
    xp[bb] = xtop + ((size_t)((b0 + bb) * 128)) * 512;
  for (int i = ic * 16; i < ic * 16 + 16; ++i) {
    float xrv[4], xiv[4];
    #pragma unroll
    for (int bb = 0; bb < 4; ++bb) {
      xrv[bb] = xp[bb][i * 512 + t * 2];
      xiv[bb] = xp[bb][i * 512 + t * 2 + 1];
    }
    #pragma unroll
    for (int oo = 0; oo < 4; ++oo) {
      size_t di = (size_t)((o0 + oo) * 128 + i) * 256 + t;
      float dr = wre[di], dj = wim[di];
      #pragma unroll
      for (int bb = 0; bb < 4; ++bb) {
        ar[bb][oo] += dr * xrv[bb] - dj * xiv[bb];
        ai[bb][oo] += dr * xiv[bb] + dj * xrv[bb];
      }
    }
  }
  if (ic == 0) {
    float zr[4][8], zi[4][8];
    #pragma unroll
    for (int bb = 0; bb < 4; ++bb)
      #pragma unroll
      for (int r = 0; r < 8; ++r) {
        zr[bb][r] = z[(b0 + bb) * 16 + r * 2];
        zi[bb][r] = z[(b0 + bb) * 16 + r * 2 + 1];
      }
    #pragma unroll
    for (int oo = 0; oo < 4; ++oo)
      #pragma unroll
      for (int r = 0; r < 8; ++r) {
        float urv = ure[(size_t)((o0 + oo) * 8 + r) * 256 + t];
        float uiv = uim[(size_t)((o0 + oo) * 8 + r) * 256 + t];
        #pragma unroll
        for (int bb = 0; bb < 4; ++bb) {
          ar[bb][oo] += urv * zr[bb][r] - uiv * zi[bb][r];
          ai[bb][oo] += urv * zi[bb][r] + uiv * zr[bb][r];
        }
      }
  }
  #pragma unroll
  for (int bb = 0; bb < 4; ++bb)
    #pragma unroll
    for (int oo = 0; oo < 4; ++oo) {
      size_t oi = ((size_t)((b0 + bb) * 128 + o0 + oo) * 256 + (size_t)t) * 2;
      atomicAdd(&otop[oi], ar[bb][oo]);
      atomicAdd(&otop[oi + 1], ai[bb][oo]);
    }
}

// Fused inverse-DFT + skip-GEMM + activation (byte-identical to round 12).
__global__ __launch_bounds__(256) void k_out(const float* __restrict__ x,
                                             const unsigned short* __restrict__ swf,
                                             const unsigned short* __restrict__ t2f,
                                             const float* __restrict__ otop,
                                             const float* __restrict__ tab,
                                             float* __restrict__ out) {
  __shared__ unsigned short Ylds[128 * 36];              // [o][k]
  __shared__ unsigned short Bh[128 * 36], Bl[128 * 36];  // x tile [w][c_local]
  const int hd = blockIdx.x;
  const int h = ((hd & 7) << 4) | (hd >> 3);   // bijective XCD swizzle (128 % 8 == 0)
  const int b = blockIdx.y;
  const int t = threadIdx.x;
  const int lane = t & 63, wv = t >> 6;
  const int kh8 = (lane >> 5) * 8;
  const int col = lane & 31;
  const int o_lane = wv * 32 + col;

  // ---- I1: Y[o][n] = sum_m X[o][m][n] e^{+2pi i m h/128} (fp32) ----
  {
    int o = t >> 1, nh = (t & 1) * 8;
    float yr[8], yi[8];
    #pragma unroll
    for (int j = 0; j < 8; ++j) { yr[j] = 0.f; yi[j] = 0.f; }
    const float* xb = otop + ((size_t)(b * 128 + o)) * 512 + nh * 2;
    #pragma unroll 4
    for (int m = 0; m < 16; ++m) {
      float cm = tab[4096 + h * 16 + m];   // uniform -> s_load
      float sm = tab[6144 + h * 16 + m];
      float4 q0 = *(const float4*)(xb + m * 32 + 0);
      float4 q1 = *(const float4*)(xb + m * 32 + 4);
      float4 q2 = *(const float4*)(xb + m * 32 + 8);
      float4 q3 = *(const float4*)(xb + m * 32 + 12);
      yr[0] += q0.x * cm - q0.y * sm; yi[0] += q0.x * sm + q0.y * cm;
      yr[1] += q0.z * cm - q0.w * sm; yi[1] += q0.z * sm + q0.w * cm;
      yr[2] += q1.x * cm - q1.y * sm; yi[2] += q1.x * sm + q1.y * cm;
      yr[3] += q1.z * cm - q1.w * sm; yi[3] += q1.z * sm + q1.w * cm;
      yr[4] += q2.x * cm - q2.y * sm; yi[4] += q2.x * sm + q2.y * cm;
      yr[5] += q2.z * cm - q2.w * sm; yi[5] += q2.z * sm + q2.w * cm;
      yr[6] += q3.x * cm - q3.y * sm; yi[6] += q3.x * sm + q3.y * cm;
      yr[7] += q3.z * cm - q3.w * sm; yi[7] += q3.z * sm + q3.w * cm;
    }
    #pragma unroll
    for (int j = 0; j < 8; ++j) {
      Ylds[o * 36 + nh + j] = bf_rnd(yr[j]);
      Ylds[o * 36 + 16 + nh + j] = bf_rnd(yi[j]);
    }
  }

  f32x16 acc[4];
  #pragma unroll
  for (int nt = 0; nt < 4; ++nt)
    #pragma unroll
    for (int e = 0; e < 16; ++e) acc[nt][e] = 0.f;

  const int cofs = t >> 7;       // 0 or 1
  const int wB = t & 127;
  const float* xbase = x + (size_t)b * 2097152 + (size_t)h * 128 + wB;

  // ---- skip GEMM: 4 K-chunks of 32 (loads at chunk top) ----
  #pragma unroll
  for (int kc = 0; kc < 4; ++kc) {
    float xv[16];
    #pragma unroll
    for (int it = 0; it < 16; ++it)
      xv[it] = xbase[(size_t)(kc * 32 + it * 2 + cofs) * 16384];
    bf16x8 ah[2], al[2];
    #pragma unroll
    for (int ks = 0; ks < 2; ++ks) {
      const unsigned short* base = swf + (size_t)((kc * 2 + ks) * 2) * 2048 + o_lane * 16 + kh8;
      ah[ks] = *(const bf16x8*)base;
      al[ks] = *(const bf16x8*)(base + 2048);
    }
    __syncthreads();  // prior chunk's frag reads (or I1 Ylds writes) complete
    #pragma unroll
    for (int it = 0; it < 16; ++it) {
      int cl = it * 2 + cofs;
      unsigned short hb, lb;
      bf_split(xv[it], hb, lb);
      Bh[wB * 36 + cl] = hb; Bl[wB * 36 + cl] = lb;
    }
    __syncthreads();
    #pragma unroll
    for (int ks = 0; ks < 2; ++ks) {
      const int kb = ks * 16 + kh8;
      #pragma unroll
      for (int nt = 0; nt < 4; ++nt) {
        bf16x8 bh_ = ldfrag(&Bh[(nt * 32 + col) * 36 + kb]);
        bf16x8 bl_ = ldfrag(&Bl[(nt * 32 + col) * 36 + kb]);
        acc[nt] = __builtin_amdgcn_mfma_f32_32x32x16_bf16(ah[ks], bh_, acc[nt], 0, 0, 0);
        acc[nt] = __builtin_amdgcn_mfma_f32_32x32x16_bf16(ah[ks], bl_, acc[nt], 0, 0, 0);
        acc[nt] = __builtin_amdgcn_mfma_f32_32x32x16_bf16(al[ks], bh_, acc[nt], 0, 0, 0);
      }
    }
  }

  // ---- S2: spectral I2 via MFMA into the same accumulators ----
  #pragma unroll
  for (int ks = 0; ks < 2; ++ks) {
    const int kb = ks * 16 + kh8;
    bf16x8 ya = ldfrag(&Ylds[o_lane * 36 + kb]);
    #pragma unroll
    for (int nt = 0; nt < 4; ++nt) {
      bf16x8 tb = *(const bf16x8*)(t2f + (nt * 32 + col) * 32 + kb);
      acc[nt] = __builtin_amdgcn_mfma_f32_32x32x16_bf16(ya, tb, acc[nt], 0, 0, 0);
    }
  }

  // ---- epilogue: activation + store ----
  #pragma unroll
  for (int nt = 0; nt < 4; ++nt) {
    int w = nt * 32 + col;
    #pragma unroll
    for (int r = 0; r < 16; ++r) {
      int o = wv * 32 + (r & 3) + 8 * (r >> 2) + 4 * (lane >> 5);
      float v = acc[nt][r];
      out[((size_t)(b * 128 + o)) * 16384 + (size_t)h * 128 + w] = v * __expf(-v * v);
    }
  }
}

extern "C" void kernel_launch(void* const* d_in, const int* in_sizes, int n_in,
                              void* d_out, int out_size, void* d_ws, size_t ws_size,
                              hipStream_t stream) {
  const float* x  = (const float*)d_in[0];
  const float* wr = (const float*)d_in[1];
  const float* wi = (const float*)d_in[2];
  const float* ur = (const float*)d_in[3];
  const float* ui = (const float*)d_in[4];
  const float* vr = (const float*)d_in[5];
  const float* vi = (const float*)d_in[6];
  const float* sw = (const float*)d_in[7];
  float* out  = (float*)d_out;
  float* ws   = (float*)d_ws;
  float* tab  = ws + TAB_OFF;
  float* xtop = ws + XTOP_OFF;
  float* z    = ws + Z_OFF;
  float* otop = ws + OTOP_OFF;
  unsigned short* tf  = (unsigned short*)(ws + TF_OFF);
  unsigned short* t2f = (unsigned short*)(ws + T2F_OFF);
  unsigned short* swf = (unsigned short*)(ws + SWF_OFF);

  // z and otop are adjacent: one memset covers both.
  hipMemsetAsync(z, 0, (256 + 1048576) * sizeof(float), stream);
  hipLaunchKernelGGL(k_prep, dim3(160), dim3(256), 0, stream, sw, tab, tf, t2f, swf);
  hipLaunchKernelGGL(k_fwd,  dim3(128, 16), dim3(256), 0, stream, x, tf, tab, vr, vi, xtop, z);
  hipLaunchKernelGGL(k_mix,  dim3(32, 4, 8), dim3(256), 0, stream, xtop, wr, wi, ur, ui, z, otop);
  hipLaunchKernelGGL(k_out,  dim3(128, 16), dim3(256), 0, stream, x, swf, t2f, otop, tab, out);
}

// Round 14
// 180.387 us; speedup vs baseline: 1.0559x; 1.0559x over previous
//
#include <hip/hip_runtime.h>
#include <math.h>

// B=16, C=128, H=128, W=128, MODES=16, RANK=8
// ws layout (float offsets):
//   tab  @ 0      : 8 tables of 2048 floats each
//   xtop @ 16384  : (b, i, mn, {re,im})  1,048,576 floats
//   z    @ 1064960: 256 floats
//   otop @ 1065216: 1,048,576 floats
//   tf   @ 2113792: split-bf16 F1 DFT table [part][n'][k], 8192 shorts
//   t2f  @ 2117888: bf16 I2 table in frag layout [w][n'], 4096 shorts
//   swf  @ 2119936: split-bf16 skip_w in MFMA A-frag order, 32768 shorts
#define TAB_OFF 0
#define XTOP_OFF 16384
#define Z_OFF (16384 + 1048576)
#define OTOP_OFF (Z_OFF + 256)
#define TF_OFF (OTOP_OFF + 1048576)
#define T2F_OFF (TF_OFF + 4096)
#define SWF_OFF (T2F_OFF + 2048)

using bf16x8 = __attribute__((ext_vector_type(8))) short;
using s16x4  = __attribute__((ext_vector_type(4))) short;
using f32x16 = __attribute__((ext_vector_type(16))) float;

__device__ inline unsigned short bf_rnd(float v) {
  return (unsigned short)((__float_as_uint(v) + 0x8000u) >> 16);
}
__device__ inline void bf_split(float v, unsigned short& hi, unsigned short& lo) {
  unsigned u = __float_as_uint(v);
  hi = (unsigned short)(u >> 16);
  float r = v - __uint_as_float(u & 0xFFFF0000u);
  lo = (unsigned short)(__float_as_uint(r) >> 16);
}
__device__ inline bf16x8 ldfrag(const unsigned short* p) {
  s16x4 a = *(const s16x4*)p;        // ds_read_b64 (8B aligned)
  s16x4 b = *(const s16x4*)(p + 4);
  bf16x8 r;
  r[0] = a[0]; r[1] = a[1]; r[2] = a[2]; r[3] = a[3];
  r[4] = b[0]; r[5] = b[1]; r[6] = b[2]; r[7] = b[3];
  return r;
}
__device__ inline bf16x8 ldfrag_sw(const unsigned short* base, int row, int koff) {
  int byte = row * 256 + ((koff * 2) ^ ((row & 7) << 4));
  return ldfrag((const unsigned short*)((const char*)base + byte));
}

// One merged prep kernel: tab | tf | t2f | swf tables, PLUS grid-stride
// zeroing of z+otop (replaces the hipMemsetAsync dispatch).
__global__ __launch_bounds__(256) void k_prep(const float* __restrict__ sw,
                                              float* __restrict__ tab,
                                              unsigned short* __restrict__ tf,
                                              unsigned short* __restrict__ t2f,
                                              unsigned short* __restrict__ swf,
                                              float4* __restrict__ zdst) {
  int idx = blockIdx.x * 256 + threadIdx.x;   // [0, 40960)
  // ---- zero z + otop (1,048,832 floats = 262,208 float4) ----
  for (int i = idx; i < 262208; i += 40960)
    zdst[i] = make_float4(0.f, 0.f, 0.f, 0.f);

  if (idx < 16384) {
    int which = idx >> 11, rem = idx & 2047;
    int a, j;
    if (which == 4 || which == 5) { a = rem & 127; j = rem >> 7; }  // [m][h]
    else { a = rem >> 4; j = rem & 15; }
    int p = (a * j) & 127;
    float ang = (float)p * (float)(3.14159265358979323846 / 64.0);
    float cv = cosf(ang), sv = sinf(ang);
    float v;
    switch (which) {
      case 0: v = cv * (1.f / 128.f); break;
      case 1: v = -sv * (1.f / 128.f); break;
      case 2: v = cv; break;
      case 3: v = sv; break;
      case 4: v = cv; break;
      case 5: v = sv; break;
      case 6: v = ((rem & 15) == 0 ? 1.f : 2.f) * cv * (1.f / 128.f); break;
      default: v = ((rem & 15) == 0 ? 1.f : 2.f) * (-sv) * (1.f / 128.f); break;
    }
    tab[idx] = v;
  } else if (idx < 20480) {
    int r = idx - 16384;                       // [0,4096)
    int np = r >> 7, k = r & 127;
    int n = np & 15;
    int p = (k * n) & 127;
    float ang = (float)p * (float)(3.14159265358979323846 / 64.0);
    float v = (np < 16 ? cosf(ang) : -sinf(ang)) * (1.f / 128.f);
    unsigned short hi, lo;
    bf_split(v, hi, lo);
    tf[np * 128 + k] = hi;
    tf[4096 + np * 128 + k] = lo;
  } else if (idx < 24576) {
    int r = idx - 20480;                       // [0,4096)
    int w = r >> 5, np = r & 31;
    int n = np & 15;
    int p = (w * n) & 127;
    float ang = (float)p * (float)(3.14159265358979323846 / 64.0);
    float cn = (n == 0) ? 1.f : 2.f;
    float v = (np < 16 ? cosf(ang) : -sinf(ang)) * cn * (1.f / 128.f);
    t2f[r] = bf_rnd(v);
  } else if (idx < 40960) {
    int r = idx - 24576;                       // [0,16384)
    int o = r >> 7, k = r & 127;
    unsigned short hb, lb;
    bf_split(sw[o * 128 + k], hb, lb);
    int kc = k >> 5, ks = (k >> 4) & 1, kh = (k >> 3) & 1, j = k & 7;
    int f0 = (kc * 2 + ks) * 2;
    swf[(f0 + 0) * 2048 + o * 16 + kh * 8 + j] = hb;
    swf[(f0 + 1) * 2048 + o * 16 + kh * 8 + j] = lb;
  }
}

// Forward truncated DFT via MFMA + fused z-partials (verified round 11).
// NEW vs r13: XCD-aware c-swizzle (the mechanism verified on k_out in r12) —
// each XCD reads 16 consecutive 64KB x-slices instead of 8-way interleave.
__global__ __launch_bounds__(256) void k_fwd(const float* __restrict__ x,
                                             const unsigned short* __restrict__ tf,
                                             const float* __restrict__ tab,
                                             const float* __restrict__ vre,
                                             const float* __restrict__ vim,
                                             float* __restrict__ xtop,
                                             float* __restrict__ zout) {
  __shared__ unsigned short Xh[128 * 128];
  __shared__ unsigned short Tfh[32 * 128];
  __shared__ unsigned short Tfl[32 * 128];
  __shared__ float red[4][16];
  const int cd = blockIdx.x;
  const int c = ((cd & 7) << 4) | (cd >> 3);   // bijective XCD swizzle (128 % 8 == 0)
  const int b = blockIdx.y;
  const int t = threadIdx.x;
  const int lane = t & 63, wv = t >> 6;

  #pragma unroll
  for (int it = 0; it < 32; ++it) {
    int idx = it * 256 + t;
    int part = idx >> 12, rem = idx & 4095;
    int row = rem >> 7, k = rem & 127;
    unsigned short v = tf[part * 4096 + rem];
    unsigned short* dst = part ? Tfl : Tfh;
    *(unsigned short*)((char*)dst + row * 256 + ((k * 2) ^ ((row & 7) << 4))) = v;
  }
  const float* img = x + (((size_t)(b * 128 + c)) << 14);
  #pragma unroll
  for (int it = 0; it < 16; ++it) {
    int flat = it * 256 + t;
    int h = flat >> 5, wq = flat & 31;
    float4 v = *(const float4*)(img + (size_t)flat * 4);
    s16x4 pk;
    pk[0] = (short)bf_rnd(v.x); pk[1] = (short)bf_rnd(v.y);
    pk[2] = (short)bf_rnd(v.z); pk[3] = (short)bf_rnd(v.w);
    *(s16x4*)((char*)Xh + h * 256 + ((wq * 8) ^ ((h & 7) << 4))) = pk;
  }
  __syncthreads();

  f32x16 acc;
  #pragma unroll
  for (int e = 0; e < 16; ++e) acc[e] = 0.f;
  const int orow = wv * 32 + (lane & 31);
  const int bcol = lane & 31;
  const int kh8 = (lane >> 5) * 8;
  #pragma unroll
  for (int kc8 = 0; kc8 < 8; ++kc8) {
    int kfull = kc8 * 16 + kh8;
    bf16x8 a  = ldfrag_sw(Xh, orow, kfull);
    bf16x8 th = ldfrag_sw(Tfh, bcol, kfull);
    bf16x8 tl = ldfrag_sw(Tfl, bcol, kfull);
    acc = __builtin_amdgcn_mfma_f32_32x32x16_bf16(a, th, acc, 0, 0, 0);
    acc = __builtin_amdgcn_mfma_f32_32x32x16_bf16(a, tl, acc, 0, 0, 0);
  }
  __syncthreads();

  float* Arp = (float*)Xh;          // [16][132]
  float* Aip = Arp + 16 * 132;
  {
    const int col = lane & 31;
    #pragma unroll
    for (int r = 0; r < 16; ++r) {
      int h = wv * 32 + (r & 3) + 8 * (r >> 2) + 4 * (lane >> 5);
      if (col < 16) Arp[col * 132 + h] = acc[r];
      else          Aip[(col - 16) * 132 + h] = acc[r];
    }
  }
  __syncthreads();

  // ---- F2: thread t -> (m=t>>4, n=t&15), i.e. mn = t ----
  float xr = 0.f, xi = 0.f;
  {
    const int m = t >> 4, n = t & 15;
    const float* tc = tab + 8192 + m * 128;
    const float* ts = tab + 10240 + m * 128;
    const float* ar = Arp + n * 132;
    const float* ai = Aip + n * 132;
    #pragma unroll 8
    for (int h4 = 0; h4 < 128; h4 += 4) {
      float4 av = *(const float4*)(ar + h4);
      float4 iv = *(const float4*)(ai + h4);
      float4 cv = *(const float4*)(tc + h4);
      float4 sv = *(const float4*)(ts + h4);
      xr += av.x * cv.x + iv.x * sv.x;  xi += iv.x * cv.x - av.x * sv.x;
      xr += av.y * cv.y + iv.y * sv.y;  xi += iv.y * cv.y - av.y * sv.y;
      xr += av.z * cv.z + iv.z * sv.z;  xi += iv.z * cv.z - av.z * sv.z;
      xr += av.w * cv.w + iv.w * sv.w;  xi += iv.w * cv.w - av.w * sv.w;
    }
    size_t base = ((size_t)(b * 128 + c)) * 512 + (size_t)t * 2;
    xtop[base] = xr; xtop[base + 1] = xi;
  }

  // ---- fused z partial: z[b,r] += X[b,c,t] * conj(V)[c,r,t] ----
  {
    float zr[8], zi[8];
    #pragma unroll
    for (int r = 0; r < 8; ++r) {
      float vr = vre[(size_t)(c * 8 + r) * 256 + t];
      float vi = vim[(size_t)(c * 8 + r) * 256 + t];
      zr[r] = xr * vr + xi * vi;
      zi[r] = xi * vr - xr * vi;
    }
    #pragma unroll
    for (int r = 0; r < 8; ++r)
      for (int off = 32; off > 0; off >>= 1) {
        zr[r] += __shfl_down(zr[r], off);
        zi[r] += __shfl_down(zi[r], off);
      }
    if (lane == 0) {
      #pragma unroll
      for (int r = 0; r < 8; ++r) { red[wv][r * 2] = zr[r]; red[wv][r * 2 + 1] = zi[r]; }
    }
    __syncthreads();
    if (t < 16) atomicAdd(&zout[b * 16 + t], red[0][t] + red[1][t] + red[2][t] + red[3][t]);
  }
}

// otop partials — reverted to the round-12-verified b-pair version.
// Grid (32 o-tiles, 8 b-pairs, 8 ichunks).
__global__ __launch_bounds__(256) void k_mix(const float* __restrict__ xtop,
                                             const float* __restrict__ wre,
                                             const float* __restrict__ wim,
                                             const float* __restrict__ ure,
                                             const float* __restrict__ uim,
                                             const float* __restrict__ z,
                                             float* __restrict__ otop) {
  int o0 = blockIdx.x * 4, b0 = blockIdx.y * 2, ic = blockIdx.z, t = threadIdx.x;
  float ar[2][4], ai[2][4];
  #pragma unroll
  for (int bb = 0; bb < 2; ++bb)
    #pragma unroll
    for (int oo = 0; oo < 4; ++oo) { ar[bb][oo] = 0.f; ai[bb][oo] = 0.f; }
  const float* x0 = xtop + ((size_t)(b0 * 128)) * 512;
  const float* x1 = x0 + 128 * 512;
  for (int i = ic * 16; i < ic * 16 + 16; ++i) {
    float x0r = x0[i * 512 + t * 2], x0i = x0[i * 512 + t * 2 + 1];
    float x1r = x1[i * 512 + t * 2], x1i = x1[i * 512 + t * 2 + 1];
    #pragma unroll
    for (int oo = 0; oo < 4; ++oo) {
      size_t di = (size_t)((o0 + oo) * 128 + i) * 256 + t;
      float dr = wre[di], dj = wim[di];
      ar[0][oo] += dr * x0r - dj * x0i; ai[0][oo] += dr * x0i + dj * x0r;
      ar[1][oo] += dr * x1r - dj * x1i; ai[1][oo] += dr * x1i + dj * x1r;
    }
  }
  if (ic == 0) {
    float zr[2][8], zi[2][8];
    #pragma unroll
    for (int bb = 0; bb < 2; ++bb)
      #pragma unroll
      for (int r = 0; r < 8; ++r) {
        zr[bb][r] = z[(b0 + bb) * 16 + r * 2];
        zi[bb][r] = z[(b0 + bb) * 16 + r * 2 + 1];
      }
    #pragma unroll
    for (int oo = 0; oo < 4; ++oo)
      #pragma unroll
      for (int r = 0; r < 8; ++r) {
        float urv = ure[(size_t)((o0 + oo) * 8 + r) * 256 + t];
        float uiv = uim[(size_t)((o0 + oo) * 8 + r) * 256 + t];
        #pragma unroll
        for (int bb = 0; bb < 2; ++bb) {
          ar[bb][oo] += urv * zr[bb][r] - uiv * zi[bb][r];
          ai[bb][oo] += urv * zi[bb][r] + uiv * zr[bb][r];
        }
      }
  }
  #pragma unroll
  for (int bb = 0; bb < 2; ++bb)
    #pragma unroll
    for (int oo = 0; oo < 4; ++oo) {
      size_t oi = ((size_t)((b0 + bb) * 128 + o0 + oo) * 256 + (size_t)t) * 2;
      atomicAdd(&otop[oi], ar[bb][oo]);
      atomicAdd(&otop[oi + 1], ai[bb][oo]);
    }
}

// Fused inverse-DFT + skip-GEMM + activation (byte-identical to round 12).
__global__ __launch_bounds__(256) void k_out(const float* __restrict__ x,
                                             const unsigned short* __restrict__ swf,
                                             const unsigned short* __restrict__ t2f,
                                             const float* __restrict__ otop,
                                             const float* __restrict__ tab,
                                             float* __restrict__ out) {
  __shared__ unsigned short Ylds[128 * 36];              // [o][k]
  __shared__ unsigned short Bh[128 * 36], Bl[128 * 36];  // x tile [w][c_local]
  const int hd = blockIdx.x;
  const int h = ((hd & 7) << 4) | (hd >> 3);   // bijective XCD swizzle (128 % 8 == 0)
  const int b = blockIdx.y;
  const int t = threadIdx.x;
  const int lane = t & 63, wv = t >> 6;
  const int kh8 = (lane >> 5) * 8;
  const int col = lane & 31;
  const int o_lane = wv * 32 + col;

  // ---- I1: Y[o][n] = sum_m X[o][m][n] e^{+2pi i m h/128} (fp32) ----
  {
    int o = t >> 1, nh = (t & 1) * 8;
    float yr[8], yi[8];
    #pragma unroll
    for (int j = 0; j < 8; ++j) { yr[j] = 0.f; yi[j] = 0.f; }
    const float* xb = otop + ((size_t)(b * 128 + o)) * 512 + nh * 2;
    #pragma unroll 4
    for (int m = 0; m < 16; ++m) {
      float cm = tab[4096 + h * 16 + m];   // uniform -> s_load
      float sm = tab[6144 + h * 16 + m];
      float4 q0 = *(const float4*)(xb + m * 32 + 0);
      float4 q1 = *(const float4*)(xb + m * 32 + 4);
      float4 q2 = *(const float4*)(xb + m * 32 + 8);
      float4 q3 = *(const float4*)(xb + m * 32 + 12);
      yr[0] += q0.x * cm - q0.y * sm; yi[0] += q0.x * sm + q0.y * cm;
      yr[1] += q0.z * cm - q0.w * sm; yi[1] += q0.z * sm + q0.w * cm;
      yr[2] += q1.x * cm - q1.y * sm; yi[2] += q1.x * sm + q1.y * cm;
      yr[3] += q1.z * cm - q1.w * sm; yi[3] += q1.z * sm + q1.w * cm;
      yr[4] += q2.x * cm - q2.y * sm; yi[4] += q2.x * sm + q2.y * cm;
      yr[5] += q2.z * cm - q2.w * sm; yi[5] += q2.z * sm + q2.w * cm;
      yr[6] += q3.x * cm - q3.y * sm; yi[6] += q3.x * sm + q3.y * cm;
      yr[7] += q3.z * cm - q3.w * sm; yi[7] += q3.z * sm + q3.w * cm;
    }
    #pragma unroll
    for (int j = 0; j < 8; ++j) {
      Ylds[o * 36 + nh + j] = bf_rnd(yr[j]);
      Ylds[o * 36 + 16 + nh + j] = bf_rnd(yi[j]);
    }
  }

  f32x16 acc[4];
  #pragma unroll
  for (int nt = 0; nt < 4; ++nt)
    #pragma unroll
    for (int e = 0; e < 16; ++e) acc[nt][e] = 0.f;

  const int cofs = t >> 7;       // 0 or 1
  const int wB = t & 127;
  const float* xbase = x + (size_t)b * 2097152 + (size_t)h * 128 + wB;

  // ---- skip GEMM: 4 K-chunks of 32 (loads at chunk top) ----
  #pragma unroll
  for (int kc = 0; kc < 4; ++kc) {
    float xv[16];
    #pragma unroll
    for (int it = 0; it < 16; ++it)
      xv[it] = xbase[(size_t)(kc * 32 + it * 2 + cofs) * 16384];
    bf16x8 ah[2], al[2];
    #pragma unroll
    for (int ks = 0; ks < 2; ++ks) {
      const unsigned short* base = swf + (size_t)((kc * 2 + ks) * 2) * 2048 + o_lane * 16 + kh8;
      ah[ks] = *(const bf16x8*)base;
      al[ks] = *(const bf16x8*)(base + 2048);
    }
    __syncthreads();  // prior chunk's frag reads (or I1 Ylds writes) complete
    #pragma unroll
    for (int it = 0; it < 16; ++it) {
      int cl = it * 2 + cofs;
      unsigned short hb, lb;
      bf_split(xv[it], hb, lb);
      Bh[wB * 36 + cl] = hb; Bl[wB * 36 + cl] = lb;
    }
    __syncthreads();
    #pragma unroll
    for (int ks = 0; ks < 2; ++ks) {
      const int kb = ks * 16 + kh8;
      #pragma unroll
      for (int nt = 0; nt < 4; ++nt) {
        bf16x8 bh_ = ldfrag(&Bh[(nt * 32 + col) * 36 + kb]);
        bf16x8 bl_ = ldfrag(&Bl[(nt * 32 + col) * 36 + kb]);
        acc[nt] = __builtin_amdgcn_mfma_f32_32x32x16_bf16(ah[ks], bh_, acc[nt], 0, 0, 0);
        acc[nt] = __builtin_amdgcn_mfma_f32_32x32x16_bf16(ah[ks], bl_, acc[nt], 0, 0, 0);
        acc[nt] = __builtin_amdgcn_mfma_f32_32x32x16_bf16(al[ks], bh_, acc[nt], 0, 0, 0);
      }
    }
  }

  // ---- S2: spectral I2 via MFMA into the same accumulators ----
  #pragma unroll
  for (int ks = 0; ks < 2; ++ks) {
    const int kb = ks * 16 + kh8;
    bf16x8 ya = ldfrag(&Ylds[o_lane * 36 + kb]);
    #pragma unroll
    for (int nt = 0; nt < 4; ++nt) {
      bf16x8 tb = *(const bf16x8*)(t2f + (nt * 32 + col) * 32 + kb);
      acc[nt] = __builtin_amdgcn_mfma_f32_32x32x16_bf16(ya, tb, acc[nt], 0, 0, 0);
    }
  }

  // ---- epilogue: activation + store ----
  #pragma unroll
  for (int nt = 0; nt < 4; ++nt) {
    int w = nt * 32 + col;
    #pragma unroll
    for (int r = 0; r < 16; ++r) {
      int o = wv * 32 + (r & 3) + 8 * (r >> 2) + 4 * (lane >> 5);
      float v = acc[nt][r];
      out[((size_t)(b * 128 + o)) * 16384 + (size_t)h * 128 + w] = v * __expf(-v * v);
    }
  }
}

extern "C" void kernel_launch(void* const* d_in, const int* in_sizes, int n_in,
                              void* d_out, int out_size, void* d_ws, size_t ws_size,
                              hipStream_t stream) {
  const float* x  = (const float*)d_in[0];
  const float* wr = (const float*)d_in[1];
  const float* wi = (const float*)d_in[2];
  const float* ur = (const float*)d_in[3];
  const float* ui = (const float*)d_in[4];
  const float* vr = (const float*)d_in[5];
  const float* vi = (const float*)d_in[6];
  const float* sw = (const float*)d_in[7];
  float* out  = (float*)d_out;
  float* ws   = (float*)d_ws;
  float* tab  = ws + TAB_OFF;
  float* xtop = ws + XTOP_OFF;
  float* z    = ws + Z_OFF;
  float* otop = ws + OTOP_OFF;
  unsigned short* tf  = (unsigned short*)(ws + TF_OFF);
  unsigned short* t2f = (unsigned short*)(ws + T2F_OFF);
  unsigned short* swf = (unsigned short*)(ws + SWF_OFF);

  hipLaunchKernelGGL(k_prep, dim3(160), dim3(256), 0, stream, sw, tab, tf, t2f, swf,
                     (float4*)z);
  hipLaunchKernelGGL(k_fwd,  dim3(128, 16), dim3(256), 0, stream, x, tf, tab, vr, vi, xtop, z);
  hipLaunchKernelGGL(k_mix,  dim3(32, 8, 8), dim3(256), 0, stream, xtop, wr, wi, ur, ui, z, otop);
  hipLaunchKernelGGL(k_out,  dim3(128, 16), dim3(256), 0, stream, x, swf, t2f, otop, tab, out);
}